// Round 2
// baseline (424.640 us; speedup 1.0000x reference)
//
#include <hip/hip_runtime.h>

typedef unsigned short u16;
typedef __attribute__((ext_vector_type(8))) short short8;
typedef __attribute__((ext_vector_type(4))) float f32x4;

// Problem constants: B=2, T=2048, C=2048, H=16, HD=128
#define TSEQ 2048
#define NHEAD 16
#define HDIM 128

__device__ __forceinline__ u16 f2bf(float x) {
    unsigned u = __float_as_uint(x);
    return (u16)((u + 0x7fffu + ((u >> 16) & 1u)) >> 16);
}
__device__ __forceinline__ float b2f(u16 h) {
    return __uint_as_float(((unsigned)h) << 16);
}
__device__ __forceinline__ void async16(const void* g, void* l) {
    __builtin_amdgcn_global_load_lds((__attribute__((address_space(1))) void*)(void*)g,
                                     (__attribute__((address_space(3))) void*)l, 16, 0, 0);
}
__device__ __forceinline__ f32x4 zero4() {
    f32x4 z = {0.f, 0.f, 0.f, 0.f};
    return z;
}

// DPP cross-lane (16-lane group reductions), no LDS traffic
template <int CTRL>
__device__ __forceinline__ float dppf(float x) {
    return __int_as_float(__builtin_amdgcn_mov_dpp(__float_as_int(x), CTRL, 0xf, 0xf, true));
}
__device__ __forceinline__ float dpp_max16(float x) {
    x = fmaxf(x, dppf<0xB1>(x));   // quad_perm xor1
    x = fmaxf(x, dppf<0x4E>(x));   // quad_perm xor2
    x = fmaxf(x, dppf<0x141>(x));  // row_half_mirror (~xor4)
    x = fmaxf(x, dppf<0x140>(x));  // row_mirror (~xor8)
    return x;
}
__device__ __forceinline__ float dpp_sum16(float x) {
    x += dppf<0xB1>(x);
    x += dppf<0x4E>(x);
    x += dppf<0x141>(x);
    x += dppf<0x140>(x);
    return x;
}

// ---------------- cast x (f32 -> bf16), vectorized ----------------
__global__ void cast_bf16(const float4* __restrict__ in, ushort4* __restrict__ out, int n4) {
    int i = blockIdx.x * 256 + threadIdx.x;
    if (i < n4) {
        float4 v = in[i];
        ushort4 o;
        o.x = f2bf(v.x); o.y = f2bf(v.y); o.z = f2bf(v.z); o.w = f2bf(v.w);
        out[i] = o;
    }
}

// ---------------- transpose + cast: in f32 [K][N] -> out bf16 [N][K] ----------------
__global__ void transpose_cast(const float* __restrict__ in, u16* __restrict__ out, int K, int N) {
    __shared__ float tile[64][65];
    int n0 = blockIdx.x * 64, k0 = blockIdx.y * 64;
    int tx = threadIdx.x & 63, ty = threadIdx.x >> 6;
#pragma unroll
    for (int i = 0; i < 16; i++) {
        int r = ty + i * 4;
        tile[r][tx] = in[(size_t)(k0 + r) * N + n0 + tx];
    }
    __syncthreads();
#pragma unroll
    for (int i = 0; i < 16; i++) {
        int r = ty + i * 4;
        out[(size_t)(n0 + r) * K + k0 + tx] = f2bf(tile[tx][r]);
    }
}

// ---------------- legacy 128x128 GEMM (used for the output projection, MODE 1) ----------------
template <int MODE>
__global__ __launch_bounds__(256) void gemm_bt(
    const u16* __restrict__ A, const u16* __restrict__ Bt, const float* __restrict__ bias,
    float* __restrict__ outf, u16* __restrict__ qb, u16* __restrict__ kb, u16* __restrict__ vT,
    const float* __restrict__ cosp, const float* __restrict__ sinp,
    int M, int N, int K) {
    __shared__ __align__(16) u16 smem[8704];
    u16* As = smem;            // 128*32 u16
    u16* Bs = smem + 4096;     // 128*32 u16
    const int tid = threadIdx.x;
    const int wave = tid >> 6, lane = tid & 63;
    const int low = lane & 15, quad = lane >> 4;
    const int m0 = blockIdx.y * 128, n0 = blockIdx.x * 128;
    const int wm = (wave >> 1) * 64, wn = (wave & 1) * 64;
    const int ldr = lane >> 2;
    const int ldc = (lane & 3) * 8;

    f32x4 acc[4][4];
#pragma unroll
    for (int i = 0; i < 4; i++)
#pragma unroll
        for (int j = 0; j < 4; j++) acc[i][j] = zero4();

    for (int k0 = 0; k0 < K; k0 += 32) {
#pragma unroll
        for (int c = 0; c < 2; ++c) {
            const int chunk = wave * 2 + c;
            const int row = chunk * 16 + ldr;
            async16(A + (size_t)(m0 + row) * K + k0 + ldc, As + chunk * 512);
            async16(Bt + (size_t)(n0 + row) * K + k0 + ldc, Bs + chunk * 512);
        }
        __syncthreads();
        short8 af[4], bfv[4];
#pragma unroll
        for (int i = 0; i < 4; i++) af[i] = *(const short8*)(As + (wm + i * 16 + low) * 32 + quad * 8);
#pragma unroll
        for (int j = 0; j < 4; j++) bfv[j] = *(const short8*)(Bs + (wn + j * 16 + low) * 32 + quad * 8);
#pragma unroll
        for (int i = 0; i < 4; i++)
#pragma unroll
            for (int j = 0; j < 4; j++)
                acc[i][j] = __builtin_amdgcn_mfma_f32_16x16x32_bf16(af[i], bfv[j], acc[i][j], 0, 0, 0);
        __syncthreads();
    }

    if (MODE == 1) {
#pragma unroll
        for (int j = 0; j < 4; j++) {
            const int ng = n0 + wn + j * 16 + low;
            const float bv = bias[ng];
#pragma unroll
            for (int i = 0; i < 4; i++) {
                const int rbase = m0 + wm + i * 16 + quad * 4;
#pragma unroll
                for (int r = 0; r < 4; r++)
                    outf[(size_t)(rbase + r) * N + ng] = acc[i][j][r] + bv;
            }
        }
        return;
    }
}

// ---------------- 256x256 8-phase GEMM (QKV, fused RoPE + v-transpose epilogue) ----------------
// T2 (slot^row&7 LDS swizzle, both-sides) + T3/T4 (8-phase, counted vmcnt at ph4/ph8)
// + T5 (setprio around MFMA clusters). 8 waves = 2M x 4N, per-wave 128x64, BK=64.
// LDS: 2 x (A 256x64 + B 256x64) bf16 = 128 KiB (dynamic). 1 block/CU.
// R1: stage schedule rebalanced for >=3-phase stage->drain leads:
//   ph4: e2.{A0,B0}; ph5: e2.{A1,B1}; ph8: o2 all 4 halves.
//   Drains: ph4 vmcnt(4) (tile-o, staged prev ph8, 4-phase lead);
//           ph8 vmcnt(8) (tile-e2, staged ph4/5, 3-4 phase lead; o2 stays in flight).

#define PH_PRE()                                           \
    {                                                      \
        __builtin_amdgcn_s_barrier();                      \
        asm volatile("s_waitcnt lgkmcnt(0)" ::: "memory"); \
        __builtin_amdgcn_sched_barrier(0);                 \
        __builtin_amdgcn_s_setprio(1);                     \
    }
#define PH_POST()                       \
    {                                   \
        __builtin_amdgcn_s_setprio(0);  \
        __builtin_amdgcn_s_barrier();   \
    }
#define PH_POSTV(N)                                            \
    {                                                          \
        __builtin_amdgcn_s_setprio(0);                         \
        asm volatile("s_waitcnt vmcnt(" #N ")" ::: "memory");  \
        __builtin_amdgcn_s_barrier();                          \
    }

// stage one 128-row half-tile: 2 x global_load_lds per wave (16 KiB total across 8 waves).
// LDS dest linear; global source pre-swizzled: slot = (lane&7) ^ (row&7)  (rule #21).
#define STAGE(GP, GROW0, LB, KT)                                                                     \
    {                                                                                                \
        const int ktc__ = ((KT) < NT ? (KT) : NT - 1);                                               \
        const u16* g0__ = (GP) + (size_t)((GROW0) + wave * 16 + grow) * (size_t)K + ktc__ * 64 +     \
                          gslot * 8;                                                                 \
        u16* l0__ = (LB) + wave * 1024;                                                              \
        async16(g0__, l0__);                                                                         \
        async16(g0__ + (size_t)8 * K, l0__ + 512);                                                   \
    }

#define LDA4(BASE, MB)                                                              \
    {                                                                               \
        _Pragma("unroll") for (int mm = 0; mm < 4; ++mm) {                          \
            a[mm][0] = *(const short8*)((BASE) + aoff0 + ((MB) + mm) * 1024);       \
            a[mm][1] = *(const short8*)((BASE) + aoff1 + ((MB) + mm) * 1024);       \
        }                                                                           \
    }
#define LDB2(BASE, NB)                                                              \
    {                                                                               \
        _Pragma("unroll") for (int nn = 0; nn < 2; ++nn) {                          \
            b[(NB) + nn][0] = *(const short8*)((BASE) + boff0 + ((NB) + nn) * 1024);\
            b[(NB) + nn][1] = *(const short8*)((BASE) + boff1 + ((NB) + nn) * 1024);\
        }                                                                           \
    }
#define MFQ(MB, NB)                                                                                   \
    {                                                                                                 \
        _Pragma("unroll") for (int mm = 0; mm < 4; ++mm) _Pragma("unroll") for (int nn = 0; nn < 2;   \
                                                                                ++nn) {               \
            acc[(MB) + mm][(NB) + nn] = __builtin_amdgcn_mfma_f32_16x16x32_bf16(                      \
                a[mm][0], b[(NB) + nn][0], acc[(MB) + mm][(NB) + nn], 0, 0, 0);                       \
            acc[(MB) + mm][(NB) + nn] = __builtin_amdgcn_mfma_f32_16x16x32_bf16(                      \
                a[mm][1], b[(NB) + nn][1], acc[(MB) + mm][(NB) + nn], 0, 0, 0);                       \
        }                                                                                             \
    }

__global__ __launch_bounds__(512, 2) void gemm256(
    const u16* __restrict__ A, const u16* __restrict__ Bt, const float* __restrict__ bias,
    u16* __restrict__ qb, u16* __restrict__ kb, u16* __restrict__ vT,
    const float* __restrict__ cosp, const float* __restrict__ sinp,
    int M, int N, int K) {
    extern __shared__ u16 sm[];
    u16* const smA0 = sm;             // 256x64
    u16* const smB0 = sm + 16384;     // 256x64
    u16* const smA1 = sm + 32768;
    u16* const smB1 = sm + 49152;

    const int tid = threadIdx.x;
    const int wave = tid >> 6, lane = tid & 63;
    const int low = lane & 15, quad = lane >> 4;
    const int wr = wave >> 2, wc = wave & 3;
    const int m0 = blockIdx.y * 256, n0 = blockIdx.x * 256;
    const int NT = K >> 6;  // 64-wide K tiles

    // staging per-lane source swizzle
    const int grow = lane >> 3;            // row within 8-row chunk
    const int gslot = (lane & 7) ^ grow;   // pre-swizzled 16B slot

    // fragment-read offsets (swizzled): row*64 + ((kk*4+quad)^(row&7))*8 ; row&7 == low&7
    const int swz = low & 7;
    const int arow = (wr * 128 + low) * 64;
    const int brow = (wc * 64 + low) * 64;
    const int aoff0 = arow + ((0 + quad) ^ swz) * 8;
    const int aoff1 = arow + ((4 + quad) ^ swz) * 8;
    const int boff0 = brow + ((0 + quad) ^ swz) * 8;
    const int boff1 = brow + ((4 + quad) ^ swz) * 8;

    f32x4 acc[8][4];
#pragma unroll
    for (int i = 0; i < 8; i++)
#pragma unroll
        for (int j = 0; j < 4; j++) acc[i][j] = zero4();
    short8 a[4][2], b[4][2];

    // ---- prologue: tile0 -> buf0 (8 loads), tile1 -> buf1 (8 loads) ----
    STAGE(A, m0, smA0, 0);
    STAGE(A, m0 + 128, smA0 + 8192, 0);
    STAGE(Bt, n0, smB0, 0);
    STAGE(Bt, n0 + 128, smB0 + 8192, 0);
    STAGE(A, m0, smA1, 1);
    STAGE(A, m0 + 128, smA1 + 8192, 1);
    STAGE(Bt, n0, smB1, 1);
    STAGE(Bt, n0 + 128, smB1 + 8192, 1);
    asm volatile("s_waitcnt vmcnt(8)" ::: "memory");  // tile0 landed; tile1 (8 loads) in flight
    __builtin_amdgcn_s_barrier();

    // ---- main loop: 2 K-tiles (even->buf0, odd->buf1), 8 phases / iteration ----
#pragma unroll 1
    for (int it = 0; it < (NT >> 1); ++it) {
        const int e = it * 2;
        // ph1: reads buf0 (A mh0 + B n01)
        LDA4(smA0, 0);
        LDB2(smB0, 0);
        PH_PRE(); MFQ(0, 0); PH_POST();
        // ph2: reads buf0 (B n23)
        LDB2(smB0, 2);
        PH_PRE(); MFQ(0, 2); PH_POST();
        // ph3: reads buf0 (A mh1); buf0 reads end here
        LDA4(smA0, 4);
        PH_PRE(); MFQ(4, 2); PH_POST();
        // ph4: stage e2.{A0,B0} -> buf0 (safe: buf0 reads drained at ph3 end barrier)
        STAGE(A, m0, smA0, e + 2);
        STAGE(Bt, n0, smB0, e + 2);
        PH_PRE(); MFQ(4, 0); PH_POSTV(4);  // drain tile-o (staged prev ph8, 4-phase lead)
        // ph5: reads buf1 (A mh0 + B n01); stage e2.{A1,B1} -> buf0
        LDA4(smA1, 0);
        LDB2(smB1, 0);
        STAGE(A, m0 + 128, smA0 + 8192, e + 2);
        STAGE(Bt, n0 + 128, smB0 + 8192, e + 2);
        PH_PRE(); MFQ(0, 0); PH_POST();
        // ph6: reads buf1 (B n23)
        LDB2(smB1, 2);
        PH_PRE(); MFQ(0, 2); PH_POST();
        // ph7: reads buf1 (A mh1); buf1 reads end here
        LDA4(smA1, 4);
        PH_PRE(); MFQ(4, 2); PH_POST();
        // ph8: stage o2 (all 4 halves) -> buf1 (safe: buf1 reads drained at ph7 end barrier)
        STAGE(A, m0, smA1, e + 3);
        STAGE(A, m0 + 128, smA1 + 8192, e + 3);
        STAGE(Bt, n0, smB1, e + 3);
        STAGE(Bt, n0 + 128, smB1 + 8192, e + 3);
        PH_PRE(); MFQ(4, 0); PH_POSTV(8);  // drain tile-e2 (staged ph4/5); o2 (8) stays in flight
    }

    // drain tail prefetches before LDS reuse
    asm volatile("s_waitcnt vmcnt(0)" ::: "memory");
    __syncthreads();

    // ---- epilogue: n-tile spans 2 heads of one of {q,k,v} ----
    const int which = n0 >> 11;           // 0=q 1=k 2=v
    const int h0 = (n0 & 2047) >> 7;      // first head in tile (even)
    const int bb = m0 >> 11, t0 = m0 & 2047;
    float bvv[4];
#pragma unroll
    for (int nn = 0; nn < 4; ++nn) bvv[nn] = bias[n0 + wc * 64 + nn * 16 + low];

    if (which < 2) {
        // q/k: [bh][t][d] with fused RoPE. epi tile [256][136] bf16 per head-half.
        u16* dstb = (which == 0 ? qb : kb);
        u16* epi = sm;
#pragma unroll
        for (int hh = 0; hh < 2; ++hh) {
            if ((wc >> 1) == hh) {
#pragma unroll
                for (int mm = 0; mm < 8; ++mm)
#pragma unroll
                    for (int nn = 0; nn < 4; ++nn)
#pragma unroll
                        for (int rr = 0; rr < 4; ++rr)
                            epi[(wr * 128 + mm * 16 + quad * 4 + rr) * 136 +
                                (wc & 1) * 64 + nn * 16 + low] = f2bf(acc[mm][nn][rr] + bvv[nn]);
            }
            __syncthreads();
            {
                const int row = tid >> 1, dh = (tid & 1) * 64;
                const int t = t0 + row;
                u16* dr = dstb + (((size_t)(bb * NHEAD + h0 + hh)) * TSEQ + t) * HDIM + dh;
                u16 vals[64];
#pragma unroll
                for (int qq = 0; qq < 8; ++qq)
                    *(short8*)(vals + qq * 8) = *(const short8*)(epi + row * 136 + dh + qq * 8);
                float csv[32], snv[32];
#pragma unroll
                for (int qq = 0; qq < 8; ++qq) {
                    *(float4*)(csv + qq * 4) =
                        *(const float4*)(cosp + (size_t)t * 64 + (dh >> 1) + qq * 4);
                    *(float4*)(snv + qq * 4) =
                        *(const float4*)(sinp + (size_t)t * 64 + (dh >> 1) + qq * 4);
                }
                u16 ov[64];
#pragma unroll
                for (int pp = 0; pp < 32; ++pp) {
                    float x0 = b2f(vals[2 * pp]), x1 = b2f(vals[2 * pp + 1]);
                    ov[2 * pp] = f2bf(x0 * csv[pp] - x1 * snv[pp]);
                    ov[2 * pp + 1] = f2bf(x0 * snv[pp] + x1 * csv[pp]);
                }
#pragma unroll
                for (int qq = 0; qq < 8; ++qq)
                    *(short8*)(dr + qq * 8) = *(const short8*)(ov + qq * 8);
            }
            __syncthreads();
        }
    } else {
        // v: write transposed [bh][d][t]. epi tile [128 d][264 (256 t + pad)] per head-half.
        u16* epi = sm;
#pragma unroll
        for (int hh = 0; hh < 2; ++hh) {
            if ((wc >> 1) == hh) {
#pragma unroll
                for (int mm = 0; mm < 8; ++mm)
#pragma unroll
                    for (int nn = 0; nn < 4; ++nn)
#pragma unroll
                        for (int rr = 0; rr < 4; ++rr)
                            epi[((wc & 1) * 64 + nn * 16 + low) * 264 +
                                wr * 128 + mm * 16 + quad * 4 + rr] = f2bf(acc[mm][nn][rr] + bvv[nn]);
            }
            __syncthreads();
            {
                const int dd = tid >> 2, tc = (tid & 3) * 64;
                u16* dr = vT + ((size_t)(bb * NHEAD + h0 + hh) * HDIM + dd) * TSEQ + t0 + tc;
#pragma unroll
                for (int qq = 0; qq < 8; ++qq)
                    *(short8*)(dr + qq * 8) = *(const short8*)(epi + dd * 264 + tc + qq * 8);
            }
            __syncthreads();
        }
    }
}

// ---------------- Flash attention: LDS-staged K/V, 64-key tiles, DPP softmax ----------------
__global__ __launch_bounds__(256) void flash_attn(const u16* __restrict__ qb, const u16* __restrict__ kb,
                                                  const u16* __restrict__ vT, u16* __restrict__ y) {
    __shared__ u16 Ks[64 * 128];      // [key][d], chunks xor-swizzled by (key&7)
    __shared__ u16 Vs[128 * 64];      // [d][key], chunks xor-swizzled by (d&7)
    __shared__ u16 Ps[4][16 * 72];    // per-wave P 16x64, row stride 72
    const int tid = threadIdx.x;
    const int wave = tid >> 6, lane = tid & 63;
    const int low = lane & 15, quad = lane >> 4;
    const int bh = blockIdx.x;
    const int qt = 31 - blockIdx.y;          // longest blocks first
    const int q0 = qt * 64 + wave * 16;
    const float scale2 = 0.08838834764831845f * 1.44269504088896f;  // 1/sqrt(128) * log2(e)

    const u16* Qp = qb + ((size_t)bh * TSEQ + q0) * HDIM;
    short8 qf[4];
#pragma unroll
    for (int c = 0; c < 4; c++) qf[c] = *(const short8*)(Qp + (size_t)low * HDIM + c * 32 + quad * 8);

    f32x4 o[8];
#pragma unroll
    for (int d = 0; d < 8; d++) o[d] = zero4();
    float m_i[4], l_i[4];
#pragma unroll
    for (int r = 0; r < 4; r++) { m_i[r] = -1e30f; l_i[r] = 0.f; }

    const u16* Kb = kb + (size_t)bh * TSEQ * HDIM;
    const u16* Vb = vT + (size_t)bh * HDIM * TSEQ;
    u16* Pw = &Ps[wave][0];
    const int ntiles = qt + 1;

    const int krow = tid >> 4, kchunk = tid & 15;   // K: 16 rows x 16 chunks per issue
    const int vrow = tid >> 3, vchunk = tid & 7;    // V: 32 rows x 8 chunks per issue

    for (int kt = 0; kt < ntiles; ++kt) {
        const int kv0 = kt * 64;
#pragma unroll
        for (int j = 0; j < 4; j++) {
            const int row = j * 16 + krow;
            const int gc = kchunk ^ (row & 7);
            async16(Kb + (size_t)(kv0 + row) * HDIM + gc * 8, Ks + row * 128 + kchunk * 8);
        }
#pragma unroll
        for (int j = 0; j < 4; j++) {
            const int d = j * 32 + vrow;
            const int gc = vchunk ^ (d & 7);
            async16(Vb + (size_t)d * TSEQ + kv0 + gc * 8, Vs + d * 64 + vchunk * 8);
        }
        __syncthreads();

        // ---- QK^T: S[16q x 64k] ----
        f32x4 s[4];
#pragma unroll
        for (int h = 0; h < 4; h++) s[h] = zero4();
#pragma unroll
        for (int h = 0; h < 4; h++) {
            const int row = h * 16 + low;
#pragma unroll
            for (int c = 0; c < 4; c++) {
                const int cc = c * 4 + quad;
                short8 kf = *(const short8*)(Ks + row * 128 + (cc ^ (row & 7)) * 8);
                s[h] = __builtin_amdgcn_mfma_f32_16x16x32_bf16(qf[c], kf, s[h], 0, 0, 0);
            }
        }

        // ---- online softmax (exp2 domain), DPP reductions ----
        float alpha[4];
#pragma unroll
        for (int r = 0; r < 4; r++) {
            const int qg = q0 + quad * 4 + r;
            float sv[4];
#pragma unroll
            for (int h = 0; h < 4; h++)
                sv[h] = (kv0 + h * 16 + low <= qg) ? s[h][r] * scale2 : -1e30f;
            float mx = fmaxf(fmaxf(sv[0], sv[1]), fmaxf(sv[2], sv[3]));
            mx = dpp_max16(mx);
            float mnew = fmaxf(m_i[r], mx);
            alpha[r] = exp2f(m_i[r] - mnew);
            m_i[r] = mnew;
            float p0 = exp2f(sv[0] - mnew);
            float p1 = exp2f(sv[1] - mnew);
            float p2 = exp2f(sv[2] - mnew);
            float p3 = exp2f(sv[3] - mnew);
            float rs = (p0 + p1) + (p2 + p3);
            rs = dpp_sum16(rs);
            l_i[r] = l_i[r] * alpha[r] + rs;
            const int prow = (quad * 4 + r) * 72;
            Pw[prow + low] = f2bf(p0);
            Pw[prow + 16 + low] = f2bf(p1);
            Pw[prow + 32 + low] = f2bf(p2);
            Pw[prow + 48 + low] = f2bf(p3);
        }
        __threadfence_block();

#pragma unroll
        for (int d = 0; d < 8; ++d)
#pragma unroll
            for (int r = 0; r < 4; r++) o[d][r] *= alpha[r];

        // ---- PV ----
#pragma unroll
        for (int kc = 0; kc < 2; kc++) {
            short8 pf = *(const short8*)(Pw + low * 72 + kc * 32 + quad * 8);
#pragma unroll
            for (int dd = 0; dd < 8; ++dd) {
                const int vr = dd * 16 + low;
                const int cc = kc * 4 + quad;
                short8 vf = *(const short8*)(Vs + vr * 64 + (cc ^ (vr & 7)) * 8);
                o[dd] = __builtin_amdgcn_mfma_f32_16x16x32_bf16(pf, vf, o[dd], 0, 0, 0);
            }
        }
        __syncthreads();
    }

    const int b = bh >> 4, h = bh & 15;
#pragma unroll
    for (int r = 0; r < 4; r++) {
        float inv = 1.0f / l_i[r];
        size_t row = (size_t)(b * TSEQ + q0 + quad * 4 + r);
        u16* yp = y + row * 2048 + h * HDIM;
#pragma unroll
        for (int d = 0; d < 8; ++d) yp[d * 16 + low] = f2bf(o[d][r] * inv);
    }
}

extern "C" void kernel_launch(void* const* d_in, const int* in_sizes, int n_in,
                              void* d_out, int out_size, void* d_ws, size_t ws_size,
                              hipStream_t stream) {
    const float* x = (const float*)d_in[0];
    const float* Wa = (const float*)d_in[1];
    const float* ba = (const float*)d_in[2];
    const float* Wp = (const float*)d_in[3];
    const float* bp = (const float*)d_in[4];
    const float* cs = (const float*)d_in[5];
    const float* sn = (const float*)d_in[6];
    float* out = (float*)d_out;

    u16* xb = (u16*)d_ws;             // x bf16; reused later as y
    u16* Wab = xb + 8388608;          // W_attn^T bf16 [6144][2048]
    u16* Wpb = Wab + 12582912;        // W_proj^T bf16 [2048][2048]
    u16* qb = Wpb + 4194304;          // [bh][t][d]
    u16* kb = qb + 8388608;           // [bh][t][d]
    u16* vT = kb + 8388608;           // [bh][d][t]
    u16* y = xb;

    static bool attr_set = false;
    if (!attr_set) {
        hipFuncSetAttribute(reinterpret_cast<const void*>(gemm256),
                            hipFuncAttributeMaxDynamicSharedMemorySize, 131072);
        attr_set = true;
    }

    cast_bf16<<<8192, 256, 0, stream>>>((const float4*)x, (ushort4*)xb, 2097152);
    transpose_cast<<<dim3(96, 32), 256, 0, stream>>>(Wa, Wab, 2048, 6144);
    transpose_cast<<<dim3(32, 32), 256, 0, stream>>>(Wp, Wpb, 2048, 2048);
    gemm256<<<dim3(24, 16), 512, 131072, stream>>>(xb, Wab, ba, qb, kb, vT, cs, sn, 4096, 6144, 2048);
    flash_attn<<<dim3(32, 32), 256, 0, stream>>>(qb, kb, vT, y);
    gemm_bt<1><<<dim3(16, 32), 256, 0, stream>>>(y, Wpb, bp, out, nullptr, nullptr, nullptr, nullptr, nullptr, 4096, 2048, 2048);
}

// Round 3
// 421.298 us; speedup vs baseline: 1.0079x; 1.0079x over previous
//
#include <hip/hip_runtime.h>

typedef unsigned short u16;
typedef __attribute__((ext_vector_type(8))) short short8;
typedef __attribute__((ext_vector_type(4))) float f32x4;

// Problem constants: B=2, T=2048, C=2048, H=16, HD=128
#define TSEQ 2048
#define NHEAD 16
#define HDIM 128

__device__ __forceinline__ u16 f2bf(float x) {
    unsigned u = __float_as_uint(x);
    return (u16)((u + 0x7fffu + ((u >> 16) & 1u)) >> 16);
}
__device__ __forceinline__ float b2f(u16 h) {
    return __uint_as_float(((unsigned)h) << 16);
}
__device__ __forceinline__ void async16(const void* g, void* l) {
    __builtin_amdgcn_global_load_lds((__attribute__((address_space(1))) void*)(void*)g,
                                     (__attribute__((address_space(3))) void*)l, 16, 0, 0);
}
__device__ __forceinline__ f32x4 zero4() {
    f32x4 z = {0.f, 0.f, 0.f, 0.f};
    return z;
}

// DPP cross-lane (16-lane group reductions), no LDS traffic
template <int CTRL>
__device__ __forceinline__ float dppf(float x) {
    return __int_as_float(__builtin_amdgcn_mov_dpp(__float_as_int(x), CTRL, 0xf, 0xf, true));
}
__device__ __forceinline__ float dpp_max16(float x) {
    x = fmaxf(x, dppf<0xB1>(x));   // quad_perm xor1
    x = fmaxf(x, dppf<0x4E>(x));   // quad_perm xor2
    x = fmaxf(x, dppf<0x141>(x));  // row_half_mirror (~xor4)
    x = fmaxf(x, dppf<0x140>(x));  // row_mirror (~xor8)
    return x;
}
__device__ __forceinline__ float dpp_sum16(float x) {
    x += dppf<0xB1>(x);
    x += dppf<0x4E>(x);
    x += dppf<0x141>(x);
    x += dppf<0x140>(x);
    return x;
}

// ---------------- cast x (f32 -> bf16), vectorized ----------------
__global__ void cast_bf16(const float4* __restrict__ in, ushort4* __restrict__ out, int n4) {
    int i = blockIdx.x * 256 + threadIdx.x;
    if (i < n4) {
        float4 v = in[i];
        ushort4 o;
        o.x = f2bf(v.x); o.y = f2bf(v.y); o.z = f2bf(v.z); o.w = f2bf(v.w);
        out[i] = o;
    }
}

// ---------------- transpose + cast: in f32 [K][N] -> out bf16 [N][K] ----------------
__global__ void transpose_cast(const float* __restrict__ in, u16* __restrict__ out, int K, int N) {
    __shared__ float tile[64][65];
    int n0 = blockIdx.x * 64, k0 = blockIdx.y * 64;
    int tx = threadIdx.x & 63, ty = threadIdx.x >> 6;
#pragma unroll
    for (int i = 0; i < 16; i++) {
        int r = ty + i * 4;
        tile[r][tx] = in[(size_t)(k0 + r) * N + n0 + tx];
    }
    __syncthreads();
#pragma unroll
    for (int i = 0; i < 16; i++) {
        int r = ty + i * 4;
        out[(size_t)(n0 + r) * K + k0 + tx] = f2bf(tile[tx][r]);
    }
}

// ---------------- legacy 128x128 GEMM (used for the output projection, MODE 1) ----------------
template <int MODE>
__global__ __launch_bounds__(256) void gemm_bt(
    const u16* __restrict__ A, const u16* __restrict__ Bt, const float* __restrict__ bias,
    float* __restrict__ outf, u16* __restrict__ qb, u16* __restrict__ kb, u16* __restrict__ vT,
    const float* __restrict__ cosp, const float* __restrict__ sinp,
    int M, int N, int K) {
    __shared__ __align__(16) u16 smem[8704];
    u16* As = smem;            // 128*32 u16
    u16* Bs = smem + 4096;     // 128*32 u16
    const int tid = threadIdx.x;
    const int wave = tid >> 6, lane = tid & 63;
    const int low = lane & 15, quad = lane >> 4;
    const int m0 = blockIdx.y * 128, n0 = blockIdx.x * 128;
    const int wm = (wave >> 1) * 64, wn = (wave & 1) * 64;
    const int ldr = lane >> 2;
    const int ldc = (lane & 3) * 8;

    f32x4 acc[4][4];
#pragma unroll
    for (int i = 0; i < 4; i++)
#pragma unroll
        for (int j = 0; j < 4; j++) acc[i][j] = zero4();

    for (int k0 = 0; k0 < K; k0 += 32) {
#pragma unroll
        for (int c = 0; c < 2; ++c) {
            const int chunk = wave * 2 + c;
            const int row = chunk * 16 + ldr;
            async16(A + (size_t)(m0 + row) * K + k0 + ldc, As + chunk * 512);
            async16(Bt + (size_t)(n0 + row) * K + k0 + ldc, Bs + chunk * 512);
        }
        __syncthreads();
        short8 af[4], bfv[4];
#pragma unroll
        for (int i = 0; i < 4; i++) af[i] = *(const short8*)(As + (wm + i * 16 + low) * 32 + quad * 8);
#pragma unroll
        for (int j = 0; j < 4; j++) bfv[j] = *(const short8*)(Bs + (wn + j * 16 + low) * 32 + quad * 8);
#pragma unroll
        for (int i = 0; i < 4; i++)
#pragma unroll
            for (int j = 0; j < 4; j++)
                acc[i][j] = __builtin_amdgcn_mfma_f32_16x16x32_bf16(af[i], bfv[j], acc[i][j], 0, 0, 0);
        __syncthreads();
    }

    if (MODE == 1) {
#pragma unroll
        for (int j = 0; j < 4; j++) {
            const int ng = n0 + wn + j * 16 + low;
            const float bv = bias[ng];
#pragma unroll
            for (int i = 0; i < 4; i++) {
                const int rbase = m0 + wm + i * 16 + quad * 4;
#pragma unroll
                for (int r = 0; r < 4; r++)
                    outf[(size_t)(rbase + r) * N + ng] = acc[i][j][r] + bv;
            }
        }
        return;
    }
}

// ---------------- 256x256 8-phase GEMM (QKV, fused RoPE + v-transpose epilogue) ----------------
// T2 (slot^row&7 LDS swizzle, both-sides) + T3/T4 (8-phase, counted vmcnt) + T5 (setprio).
// 8 waves = 2M x 4N, per-wave 128x64, BK=64. LDS 128 KiB dbuf. 1 block/CU.
// R2: barrier-minimal schedule — only the 4 hazard-required barriers per iteration:
//   ph3 (buf0 reads retired -> buf0 restage ok), ph4 vmcnt(4)+bar (tile-o landed),
//   ph7 (buf1 reads retired), ph8 vmcnt(8)+bar (tile-e2 landed, o2 in flight).
// All read-after-read phase crossings are barrier-free so waves drift and
// ds_read/stage issue of one wave overlaps MFMA of the other wave on the SIMD.

#define WAIT_DS()                                          \
    {                                                      \
        asm volatile("s_waitcnt lgkmcnt(0)" ::: "memory"); \
        __builtin_amdgcn_sched_barrier(0);                 \
    }
#define PRIO_MFQ(MB, NB)                \
    {                                   \
        __builtin_amdgcn_s_setprio(1);  \
        MFQ(MB, NB);                    \
        __builtin_amdgcn_s_setprio(0);  \
    }
#define BAR() __builtin_amdgcn_s_barrier();
#define VBAR(N)                                                \
    {                                                          \
        asm volatile("s_waitcnt vmcnt(" #N ")" ::: "memory");  \
        __builtin_amdgcn_s_barrier();                          \
    }

// stage one 128-row half-tile: 2 x global_load_lds per thread (16 KiB across 8 waves).
// LDS dest linear; global source pre-swizzled: slot = (lane&7) ^ (row&7)  (rule #21).
#define STAGE(GP, GROW0, LB, KT)                                                                     \
    {                                                                                                \
        const int ktc__ = ((KT) < NT ? (KT) : NT - 1);                                               \
        const u16* g0__ = (GP) + (size_t)((GROW0) + wave * 16 + grow) * (size_t)K + ktc__ * 64 +     \
                          gslot * 8;                                                                 \
        u16* l0__ = (LB) + wave * 1024;                                                              \
        async16(g0__, l0__);                                                                         \
        async16(g0__ + (size_t)8 * K, l0__ + 512);                                                   \
    }

#define LDA4(BASE, MB)                                                              \
    {                                                                               \
        _Pragma("unroll") for (int mm = 0; mm < 4; ++mm) {                          \
            a[mm][0] = *(const short8*)((BASE) + aoff0 + ((MB) + mm) * 1024);       \
            a[mm][1] = *(const short8*)((BASE) + aoff1 + ((MB) + mm) * 1024);       \
        }                                                                           \
    }
#define LDB2(BASE, NB)                                                              \
    {                                                                               \
        _Pragma("unroll") for (int nn = 0; nn < 2; ++nn) {                          \
            b[(NB) + nn][0] = *(const short8*)((BASE) + boff0 + ((NB) + nn) * 1024);\
            b[(NB) + nn][1] = *(const short8*)((BASE) + boff1 + ((NB) + nn) * 1024);\
        }                                                                           \
    }
#define MFQ(MB, NB)                                                                                   \
    {                                                                                                 \
        _Pragma("unroll") for (int mm = 0; mm < 4; ++mm) _Pragma("unroll") for (int nn = 0; nn < 2;   \
                                                                                ++nn) {               \
            acc[(MB) + mm][(NB) + nn] = __builtin_amdgcn_mfma_f32_16x16x32_bf16(                      \
                a[mm][0], b[(NB) + nn][0], acc[(MB) + mm][(NB) + nn], 0, 0, 0);                       \
            acc[(MB) + mm][(NB) + nn] = __builtin_amdgcn_mfma_f32_16x16x32_bf16(                      \
                a[mm][1], b[(NB) + nn][1], acc[(MB) + mm][(NB) + nn], 0, 0, 0);                       \
        }                                                                                             \
    }

__global__ __launch_bounds__(512, 2) void gemm256(
    const u16* __restrict__ A, const u16* __restrict__ Bt, const float* __restrict__ bias,
    u16* __restrict__ qb, u16* __restrict__ kb, u16* __restrict__ vT,
    const float* __restrict__ cosp, const float* __restrict__ sinp,
    int M, int N, int K) {
    extern __shared__ u16 sm[];
    u16* const smA0 = sm;             // 256x64
    u16* const smB0 = sm + 16384;     // 256x64
    u16* const smA1 = sm + 32768;
    u16* const smB1 = sm + 49152;

    const int tid = threadIdx.x;
    const int wave = tid >> 6, lane = tid & 63;
    const int low = lane & 15, quad = lane >> 4;
    const int wr = wave >> 2, wc = wave & 3;
    const int m0 = blockIdx.y * 256, n0 = blockIdx.x * 256;
    const int NT = K >> 6;  // 64-wide K tiles

    // staging per-lane source swizzle
    const int grow = lane >> 3;            // row within 8-row chunk
    const int gslot = (lane & 7) ^ grow;   // pre-swizzled 16B slot

    // fragment-read offsets (swizzled): row*64 + ((kk*4+quad)^(row&7))*8 ; row&7 == low&7
    const int swz = low & 7;
    const int arow = (wr * 128 + low) * 64;
    const int brow = (wc * 64 + low) * 64;
    const int aoff0 = arow + ((0 + quad) ^ swz) * 8;
    const int aoff1 = arow + ((4 + quad) ^ swz) * 8;
    const int boff0 = brow + ((0 + quad) ^ swz) * 8;
    const int boff1 = brow + ((4 + quad) ^ swz) * 8;

    f32x4 acc[8][4];
#pragma unroll
    for (int i = 0; i < 8; i++)
#pragma unroll
        for (int j = 0; j < 4; j++) acc[i][j] = zero4();
    short8 a[4][2], b[4][2];

    // ---- prologue: tile0 -> buf0 (8 loads/thread... 2/thread x4 stages), tile1 -> buf1 ----
    STAGE(A, m0, smA0, 0);
    STAGE(A, m0 + 128, smA0 + 8192, 0);
    STAGE(Bt, n0, smB0, 0);
    STAGE(Bt, n0 + 128, smB0 + 8192, 0);
    STAGE(A, m0, smA1, 1);
    STAGE(A, m0 + 128, smA1 + 8192, 1);
    STAGE(Bt, n0, smB1, 1);
    STAGE(Bt, n0 + 128, smB1 + 8192, 1);
    asm volatile("s_waitcnt vmcnt(8)" ::: "memory");  // tile0 landed; tile1 (8 loads) in flight
    __builtin_amdgcn_s_barrier();

    // ---- main loop: 2 K-tiles (even->buf0, odd->buf1), 4 barriers / iteration ----
#pragma unroll 1
    for (int it = 0; it < (NT >> 1); ++it) {
        const int e = it * 2;
        // ph1: reads buf0 (A mh0 + B n01)
        LDA4(smA0, 0);
        LDB2(smB0, 0);
        WAIT_DS(); PRIO_MFQ(0, 0);
        // ph2: reads buf0 (B n23)
        LDB2(smB0, 2);
        WAIT_DS(); PRIO_MFQ(0, 2);
        // ph3: reads buf0 (A mh1) -- last buf0 reads; barrier once data retired to regs
        LDA4(smA0, 4);
        WAIT_DS();
        BAR();  // all buf0 reads complete chip-wide -> buf0 restage may begin
        PRIO_MFQ(4, 2);
        // ph4: stage e2.{A0,B0} -> buf0 ; MFMA from regs (a from ph3, b from ph1)
        STAGE(A, m0, smA0, e + 2);
        STAGE(Bt, n0, smB0, e + 2);
        PRIO_MFQ(4, 0);
        VBAR(4);  // drain tile-o (prev ph8's 8 loads) so buf1 is readable by ALL waves
        // ph5: reads buf1 (A mh0 + B n01); stage e2.{A1,B1} -> buf0
        LDA4(smA1, 0);
        LDB2(smB1, 0);
        STAGE(A, m0 + 128, smA0 + 8192, e + 2);
        STAGE(Bt, n0 + 128, smB0 + 8192, e + 2);
        WAIT_DS(); PRIO_MFQ(0, 0);
        // ph6: reads buf1 (B n23)
        LDB2(smB1, 2);
        WAIT_DS(); PRIO_MFQ(0, 2);
        // ph7: reads buf1 (A mh1) -- last buf1 reads
        LDA4(smA1, 4);
        WAIT_DS();
        BAR();  // all buf1 reads complete -> buf1 restage may begin
        PRIO_MFQ(4, 2);
        // ph8: stage o2 (all 4 halves) -> buf1 ; MFMA from regs
        STAGE(A, m0, smA1, e + 3);
        STAGE(A, m0 + 128, smA1 + 8192, e + 3);
        STAGE(Bt, n0, smB1, e + 3);
        STAGE(Bt, n0 + 128, smB1 + 8192, e + 3);
        PRIO_MFQ(4, 0);
        VBAR(8);  // drain tile-e2 (ph4's 4 + ph5's 4); o2's 8 stay in flight
    }

    // drain tail prefetches before LDS reuse
    asm volatile("s_waitcnt vmcnt(0)" ::: "memory");
    __syncthreads();

    // ---- epilogue: n-tile spans 2 heads of one of {q,k,v} ----
    const int which = n0 >> 11;           // 0=q 1=k 2=v
    const int h0 = (n0 & 2047) >> 7;      // first head in tile (even)
    const int bb = m0 >> 11, t0 = m0 & 2047;
    float bvv[4];
#pragma unroll
    for (int nn = 0; nn < 4; ++nn) bvv[nn] = bias[n0 + wc * 64 + nn * 16 + low];

    if (which < 2) {
        // q/k: [bh][t][d] with fused RoPE. epi tile [256][136] bf16 per head-half.
        u16* dstb = (which == 0 ? qb : kb);
        u16* epi = sm;
#pragma unroll
        for (int hh = 0; hh < 2; ++hh) {
            if ((wc >> 1) == hh) {
#pragma unroll
                for (int mm = 0; mm < 8; ++mm)
#pragma unroll
                    for (int nn = 0; nn < 4; ++nn)
#pragma unroll
                        for (int rr = 0; rr < 4; ++rr)
                            epi[(wr * 128 + mm * 16 + quad * 4 + rr) * 136 +
                                (wc & 1) * 64 + nn * 16 + low] = f2bf(acc[mm][nn][rr] + bvv[nn]);
            }
            __syncthreads();
            {
                const int row = tid >> 1, dh = (tid & 1) * 64;
                const int t = t0 + row;
                u16* dr = dstb + (((size_t)(bb * NHEAD + h0 + hh)) * TSEQ + t) * HDIM + dh;
                u16 vals[64];
#pragma unroll
                for (int qq = 0; qq < 8; ++qq)
                    *(short8*)(vals + qq * 8) = *(const short8*)(epi + row * 136 + dh + qq * 8);
                float csv[32], snv[32];
#pragma unroll
                for (int qq = 0; qq < 8; ++qq) {
                    *(float4*)(csv + qq * 4) =
                        *(const float4*)(cosp + (size_t)t * 64 + (dh >> 1) + qq * 4);
                    *(float4*)(snv + qq * 4) =
                        *(const float4*)(sinp + (size_t)t * 64 + (dh >> 1) + qq * 4);
                }
                u16 ov[64];
#pragma unroll
                for (int pp = 0; pp < 32; ++pp) {
                    float x0 = b2f(vals[2 * pp]), x1 = b2f(vals[2 * pp + 1]);
                    ov[2 * pp] = f2bf(x0 * csv[pp] - x1 * snv[pp]);
                    ov[2 * pp + 1] = f2bf(x0 * snv[pp] + x1 * csv[pp]);
                }
#pragma unroll
                for (int qq = 0; qq < 8; ++qq)
                    *(short8*)(dr + qq * 8) = *(const short8*)(ov + qq * 8);
            }
            __syncthreads();
        }
    } else {
        // v: write transposed [bh][d][t]. epi tile [128 d][264 (256 t + pad)] per head-half.
        u16* epi = sm;
#pragma unroll
        for (int hh = 0; hh < 2; ++hh) {
            if ((wc >> 1) == hh) {
#pragma unroll
                for (int mm = 0; mm < 8; ++mm)
#pragma unroll
                    for (int nn = 0; nn < 4; ++nn)
#pragma unroll
                        for (int rr = 0; rr < 4; ++rr)
                            epi[((wc & 1) * 64 + nn * 16 + low) * 264 +
                                wr * 128 + mm * 16 + quad * 4 + rr] = f2bf(acc[mm][nn][rr] + bvv[nn]);
            }
            __syncthreads();
            {
                const int dd = tid >> 2, tc = (tid & 3) * 64;
                u16* dr = vT + ((size_t)(bb * NHEAD + h0 + hh) * HDIM + dd) * TSEQ + t0 + tc;
#pragma unroll
                for (int qq = 0; qq < 8; ++qq)
                    *(short8*)(dr + qq * 8) = *(const short8*)(epi + dd * 264 + tc + qq * 8);
            }
            __syncthreads();
        }
    }
}

// ---------------- Flash attention: LDS-staged K/V, 64-key tiles, DPP softmax ----------------
__global__ __launch_bounds__(256) void flash_attn(const u16* __restrict__ qb, const u16* __restrict__ kb,
                                                  const u16* __restrict__ vT, u16* __restrict__ y) {
    __shared__ u16 Ks[64 * 128];      // [key][d], chunks xor-swizzled by (key&7)
    __shared__ u16 Vs[128 * 64];      // [d][key], chunks xor-swizzled by (d&7)
    __shared__ u16 Ps[4][16 * 72];    // per-wave P 16x64, row stride 72
    const int tid = threadIdx.x;
    const int wave = tid >> 6, lane = tid & 63;
    const int low = lane & 15, quad = lane >> 4;
    const int bh = blockIdx.x;
    const int qt = 31 - blockIdx.y;          // longest blocks first
    const int q0 = qt * 64 + wave * 16;
    const float scale2 = 0.08838834764831845f * 1.44269504088896f;  // 1/sqrt(128) * log2(e)

    const u16* Qp = qb + ((size_t)bh * TSEQ + q0) * HDIM;
    short8 qf[4];
#pragma unroll
    for (int c = 0; c < 4; c++) qf[c] = *(const short8*)(Qp + (size_t)low * HDIM + c * 32 + quad * 8);

    f32x4 o[8];
#pragma unroll
    for (int d = 0; d < 8; d++) o[d] = zero4();
    float m_i[4], l_i[4];
#pragma unroll
    for (int r = 0; r < 4; r++) { m_i[r] = -1e30f; l_i[r] = 0.f; }

    const u16* Kb = kb + (size_t)bh * TSEQ * HDIM;
    const u16* Vb = vT + (size_t)bh * HDIM * TSEQ;
    u16* Pw = &Ps[wave][0];
    const int ntiles = qt + 1;

    const int krow = tid >> 4, kchunk = tid & 15;   // K: 16 rows x 16 chunks per issue
    const int vrow = tid >> 3, vchunk = tid & 7;    // V: 32 rows x 8 chunks per issue

    for (int kt = 0; kt < ntiles; ++kt) {
        const int kv0 = kt * 64;
#pragma unroll
        for (int j = 0; j < 4; j++) {
            const int row = j * 16 + krow;
            const int gc = kchunk ^ (row & 7);
            async16(Kb + (size_t)(kv0 + row) * HDIM + gc * 8, Ks + row * 128 + kchunk * 8);
        }
#pragma unroll
        for (int j = 0; j < 4; j++) {
            const int d = j * 32 + vrow;
            const int gc = vchunk ^ (d & 7);
            async16(Vb + (size_t)d * TSEQ + kv0 + gc * 8, Vs + d * 64 + vchunk * 8);
        }
        __syncthreads();

        // ---- QK^T: S[16q x 64k] ----
        f32x4 s[4];
#pragma unroll
        for (int h = 0; h < 4; h++) s[h] = zero4();
#pragma unroll
        for (int h = 0; h < 4; h++) {
            const int row = h * 16 + low;
#pragma unroll
            for (int c = 0; c < 4; c++) {
                const int cc = c * 4 + quad;
                short8 kf = *(const short8*)(Ks + row * 128 + (cc ^ (row & 7)) * 8);
                s[h] = __builtin_amdgcn_mfma_f32_16x16x32_bf16(qf[c], kf, s[h], 0, 0, 0);
            }
        }

        // ---- online softmax (exp2 domain), DPP reductions ----
        float alpha[4];
#pragma unroll
        for (int r = 0; r < 4; r++) {
            const int qg = q0 + quad * 4 + r;
            float sv[4];
#pragma unroll
            for (int h = 0; h < 4; h++)
                sv[h] = (kv0 + h * 16 + low <= qg) ? s[h][r] * scale2 : -1e30f;
            float mx = fmaxf(fmaxf(sv[0], sv[1]), fmaxf(sv[2], sv[3]));
            mx = dpp_max16(mx);
            float mnew = fmaxf(m_i[r], mx);
            alpha[r] = exp2f(m_i[r] - mnew);
            m_i[r] = mnew;
            float p0 = exp2f(sv[0] - mnew);
            float p1 = exp2f(sv[1] - mnew);
            float p2 = exp2f(sv[2] - mnew);
            float p3 = exp2f(sv[3] - mnew);
            float rs = (p0 + p1) + (p2 + p3);
            rs = dpp_sum16(rs);
            l_i[r] = l_i[r] * alpha[r] + rs;
            const int prow = (quad * 4 + r) * 72;
            Pw[prow + low] = f2bf(p0);
            Pw[prow + 16 + low] = f2bf(p1);
            Pw[prow + 32 + low] = f2bf(p2);
            Pw[prow + 48 + low] = f2bf(p3);
        }
        __threadfence_block();

#pragma unroll
        for (int d = 0; d < 8; ++d)
#pragma unroll
            for (int r = 0; r < 4; r++) o[d][r] *= alpha[r];

        // ---- PV ----
#pragma unroll
        for (int kc = 0; kc < 2; kc++) {
            short8 pf = *(const short8*)(Pw + low * 72 + kc * 32 + quad * 8);
#pragma unroll
            for (int dd = 0; dd < 8; ++dd) {
                const int vr = dd * 16 + low;
                const int cc = kc * 4 + quad;
                short8 vf = *(const short8*)(Vs + vr * 64 + (cc ^ (vr & 7)) * 8);
                o[dd] = __builtin_amdgcn_mfma_f32_16x16x32_bf16(pf, vf, o[dd], 0, 0, 0);
            }
        }
        __syncthreads();
    }

    const int b = bh >> 4, h = bh & 15;
#pragma unroll
    for (int r = 0; r < 4; r++) {
        float inv = 1.0f / l_i[r];
        size_t row = (size_t)(b * TSEQ + q0 + quad * 4 + r);
        u16* yp = y + row * 2048 + h * HDIM;
#pragma unroll
        for (int d = 0; d < 8; ++d) yp[d * 16 + low] = f2bf(o[d][r] * inv);
    }
}

extern "C" void kernel_launch(void* const* d_in, const int* in_sizes, int n_in,
                              void* d_out, int out_size, void* d_ws, size_t ws_size,
                              hipStream_t stream) {
    const float* x = (const float*)d_in[0];
    const float* Wa = (const float*)d_in[1];
    const float* ba = (const float*)d_in[2];
    const float* Wp = (const float*)d_in[3];
    const float* bp = (const float*)d_in[4];
    const float* cs = (const float*)d_in[5];
    const float* sn = (const float*)d_in[6];
    float* out = (float*)d_out;

    u16* xb = (u16*)d_ws;             // x bf16; reused later as y
    u16* Wab = xb + 8388608;          // W_attn^T bf16 [6144][2048]
    u16* Wpb = Wab + 12582912;        // W_proj^T bf16 [2048][2048]
    u16* qb = Wpb + 4194304;          // [bh][t][d]
    u16* kb = qb + 8388608;           // [bh][t][d]
    u16* vT = kb + 8388608;           // [bh][d][t]
    u16* y = xb;

    static bool attr_set = false;
    if (!attr_set) {
        hipFuncSetAttribute(reinterpret_cast<const void*>(gemm256),
                            hipFuncAttributeMaxDynamicSharedMemorySize, 131072);
        attr_set = true;
    }

    cast_bf16<<<8192, 256, 0, stream>>>((const float4*)x, (ushort4*)xb, 2097152);
    transpose_cast<<<dim3(96, 32), 256, 0, stream>>>(Wa, Wab, 2048, 6144);
    transpose_cast<<<dim3(32, 32), 256, 0, stream>>>(Wp, Wpb, 2048, 2048);
    gemm256<<<dim3(24, 16), 512, 131072, stream>>>(xb, Wab, ba, qb, kb, vT, cs, sn, 4096, 6144, 2048);
    flash_attn<<<dim3(32, 32), 256, 0, stream>>>(qb, kb, vT, y);
    gemm_bt<1><<<dim3(16, 32), 256, 0, stream>>>(y, Wpb, bp, out, nullptr, nullptr, nullptr, nullptr, nullptr, 4096, 2048, 2048);
}

// Round 4
// 395.446 us; speedup vs baseline: 1.0738x; 1.0654x over previous
//
#include <hip/hip_runtime.h>

typedef unsigned short u16;
typedef __attribute__((ext_vector_type(8))) short short8;
typedef __attribute__((ext_vector_type(4))) float f32x4;

// Problem constants: B=2, T=2048, C=2048, H=16, HD=128
#define TSEQ 2048
#define NHEAD 16
#define HDIM 128

__device__ __forceinline__ u16 f2bf(float x) {
    unsigned u = __float_as_uint(x);
    return (u16)((u + 0x7fffu + ((u >> 16) & 1u)) >> 16);
}
__device__ __forceinline__ float b2f(u16 h) {
    return __uint_as_float(((unsigned)h) << 16);
}
__device__ __forceinline__ void async16(const void* g, void* l) {
    __builtin_amdgcn_global_load_lds((__attribute__((address_space(1))) void*)(void*)g,
                                     (__attribute__((address_space(3))) void*)l, 16, 0, 0);
}
__device__ __forceinline__ f32x4 zero4() {
    f32x4 z = {0.f, 0.f, 0.f, 0.f};
    return z;
}

// DPP cross-lane (16-lane group reductions), no LDS traffic
template <int CTRL>
__device__ __forceinline__ float dppf(float x) {
    return __int_as_float(__builtin_amdgcn_mov_dpp(__float_as_int(x), CTRL, 0xf, 0xf, true));
}
__device__ __forceinline__ float dpp_max16(float x) {
    x = fmaxf(x, dppf<0xB1>(x));   // quad_perm xor1
    x = fmaxf(x, dppf<0x4E>(x));   // quad_perm xor2
    x = fmaxf(x, dppf<0x141>(x));  // row_half_mirror (~xor4)
    x = fmaxf(x, dppf<0x140>(x));  // row_mirror (~xor8)
    return x;
}
__device__ __forceinline__ float dpp_sum16(float x) {
    x += dppf<0xB1>(x);
    x += dppf<0x4E>(x);
    x += dppf<0x141>(x);
    x += dppf<0x140>(x);
    return x;
}

// ---------------- cast x (f32 -> bf16), vectorized ----------------
__global__ void cast_bf16(const float4* __restrict__ in, ushort4* __restrict__ out, int n4) {
    int i = blockIdx.x * 256 + threadIdx.x;
    if (i < n4) {
        float4 v = in[i];
        ushort4 o;
        o.x = f2bf(v.x); o.y = f2bf(v.y); o.z = f2bf(v.z); o.w = f2bf(v.w);
        out[i] = o;
    }
}

// ---------------- transpose + cast: in f32 [K][N] -> out bf16 [N][K] ----------------
__global__ void transpose_cast(const float* __restrict__ in, u16* __restrict__ out, int K, int N) {
    __shared__ float tile[64][65];
    int n0 = blockIdx.x * 64, k0 = blockIdx.y * 64;
    int tx = threadIdx.x & 63, ty = threadIdx.x >> 6;
#pragma unroll
    for (int i = 0; i < 16; i++) {
        int r = ty + i * 4;
        tile[r][tx] = in[(size_t)(k0 + r) * N + n0 + tx];
    }
    __syncthreads();
#pragma unroll
    for (int i = 0; i < 16; i++) {
        int r = ty + i * 4;
        out[(size_t)(n0 + r) * K + k0 + tx] = f2bf(tile[tx][r]);
    }
}

// ================= shared schedule macros (T2 swizzle, barrier-light, counted vmcnt) ========
#define WAIT_DS()                                          \
    {                                                      \
        asm volatile("s_waitcnt lgkmcnt(0)" ::: "memory"); \
        __builtin_amdgcn_sched_barrier(0);                 \
    }
#define BAR() __builtin_amdgcn_s_barrier();
#define VBAR_(N)                                               \
    {                                                          \
        asm volatile("s_waitcnt vmcnt(" #N ")" ::: "memory");  \
        __builtin_amdgcn_s_barrier();                          \
    }
#define VBAR(N) VBAR_(N)

// stage one 128-row half-tile: 2 x global_load_lds per thread (16 KiB across 8 waves).
// LDS dest linear; global source pre-swizzled: slot = (lane&7) ^ (row&7)  (rule #21).
#define STAGE(GP, GROW0, LB, KT)                                                                 \
    {                                                                                            \
        const u16* g0__ = (GP) + (size_t)((GROW0) + wave * 16 + grow) * (size_t)K + (KT)*64 +    \
                          gslot * 8;                                                             \
        u16* l0__ = (LB) + wave * 1024;                                                          \
        async16(g0__, l0__);                                                                     \
        async16(g0__ + (size_t)8 * K, l0__ + 512);                                               \
    }

#define LDA4(BASE, MB)                                                              \
    {                                                                               \
        _Pragma("unroll") for (int mm = 0; mm < 4; ++mm) {                          \
            a[mm][0] = *(const short8*)((BASE) + aoff0 + ((MB) + mm) * 1024);       \
            a[mm][1] = *(const short8*)((BASE) + aoff1 + ((MB) + mm) * 1024);       \
        }                                                                           \
    }
#define LDB2(BASE, NB)                                                              \
    {                                                                               \
        _Pragma("unroll") for (int nn = 0; nn < 2; ++nn) {                          \
            b[(NB) + nn][0] = *(const short8*)((BASE) + boff0 + ((NB) + nn) * 1024);\
            b[(NB) + nn][1] = *(const short8*)((BASE) + boff1 + ((NB) + nn) * 1024);\
        }                                                                           \
    }
#define MFQ(MB, NB)                                                                                   \
    {                                                                                                 \
        _Pragma("unroll") for (int mm = 0; mm < 4; ++mm) _Pragma("unroll") for (int nn = 0; nn < 2;   \
                                                                                ++nn) {               \
            acc[(MB) + mm][(NB) + nn] = __builtin_amdgcn_mfma_f32_16x16x32_bf16(                      \
                a[mm][0], b[(NB) + nn][0], acc[(MB) + mm][(NB) + nn], 0, 0, 0);                       \
            acc[(MB) + mm][(NB) + nn] = __builtin_amdgcn_mfma_f32_16x16x32_bf16(                      \
                a[mm][1], b[(NB) + nn][1], acc[(MB) + mm][(NB) + nn], 0, 0, 0);                       \
        }                                                                                             \
    }
#define PRIO_MFQ(MB, NB)                \
    {                                   \
        __builtin_amdgcn_s_setprio(1);  \
        MFQ(MB, NB);                    \
        __builtin_amdgcn_s_setprio(0);  \
    }

// ---------------- 256x256 8-phase GEMM (QKV, fused RoPE + v-transpose epilogue) ----------------
// 8 waves = 2M x 4N, per-wave 128x64, BK=64. LDS 128 KiB dbuf. 1 block/CU.
// R3: compiler-counted lgkm (b23 issued early), last iteration peeled (no stage clamp).
__global__ __launch_bounds__(512, 2) void gemm256(
    const u16* __restrict__ A, const u16* __restrict__ Bt, const float* __restrict__ bias,
    u16* __restrict__ qb, u16* __restrict__ kb, u16* __restrict__ vT,
    const float* __restrict__ cosp, const float* __restrict__ sinp,
    int M, int N, int K) {
    extern __shared__ u16 sm[];
    u16* const smA0 = sm;             // 256x64
    u16* const smB0 = sm + 16384;     // 256x64
    u16* const smA1 = sm + 32768;
    u16* const smB1 = sm + 49152;

    const int tid = threadIdx.x;
    const int wave = tid >> 6, lane = tid & 63;
    const int low = lane & 15, quad = lane >> 4;
    const int wr = wave >> 2, wc = wave & 3;
    const int m0 = blockIdx.y * 256, n0 = blockIdx.x * 256;
    const int NT = K >> 6;  // 64-wide K tiles

    const int grow = lane >> 3;            // row within 8-row chunk
    const int gslot = (lane & 7) ^ grow;   // pre-swizzled 16B slot

    const int swz = low & 7;
    const int arow = (wr * 128 + low) * 64;
    const int brow = (wc * 64 + low) * 64;
    const int aoff0 = arow + ((0 + quad) ^ swz) * 8;
    const int aoff1 = arow + ((4 + quad) ^ swz) * 8;
    const int boff0 = brow + ((0 + quad) ^ swz) * 8;
    const int boff1 = brow + ((4 + quad) ^ swz) * 8;

    f32x4 acc[8][4];
#pragma unroll
    for (int i = 0; i < 8; i++)
#pragma unroll
        for (int j = 0; j < 4; j++) acc[i][j] = zero4();
    short8 a[4][2], b[4][2];

    // ---- prologue: tile0 -> buf0, tile1 -> buf1 ----
    STAGE(A, m0, smA0, 0);
    STAGE(A, m0 + 128, smA0 + 8192, 0);
    STAGE(Bt, n0, smB0, 0);
    STAGE(Bt, n0 + 128, smB0 + 8192, 0);
    STAGE(A, m0, smA1, 1);
    STAGE(A, m0 + 128, smA1 + 8192, 1);
    STAGE(Bt, n0, smB1, 1);
    STAGE(Bt, n0 + 128, smB1 + 8192, 1);
    VBAR(8);  // tile0 landed; tile1 (8 loads) in flight

    const int NI = (NT >> 1) - 1;
#pragma unroll 1
    for (int it = 0; it < NI; ++it) {
        const int e = it * 2;
        // ---- K-tile e (buf0) ----
        LDA4(smA0, 0);
        LDB2(smB0, 0);
        LDB2(smB0, 2);
        PRIO_MFQ(0, 0);
        PRIO_MFQ(0, 2);
        LDA4(smA0, 4);
        WAIT_DS();
        BAR();  // all buf0 reads complete chip-wide -> buf0 restage may begin
        PRIO_MFQ(4, 2);
        STAGE(A, m0, smA0, e + 2);
        STAGE(Bt, n0, smB0, e + 2);
        PRIO_MFQ(4, 0);
        VBAR(4);  // drain tile e+1 (prev ph8's 8 loads); e+2's 4 stay in flight
        // ---- K-tile e+1 (buf1) ----
        LDA4(smA1, 0);
        LDB2(smB1, 0);
        LDB2(smB1, 2);
        STAGE(A, m0 + 128, smA0 + 8192, e + 2);
        STAGE(Bt, n0 + 128, smB0 + 8192, e + 2);
        PRIO_MFQ(0, 0);
        PRIO_MFQ(0, 2);
        LDA4(smA1, 4);
        WAIT_DS();
        BAR();  // all buf1 reads complete -> buf1 restage may begin
        PRIO_MFQ(4, 2);
        STAGE(A, m0, smA1, e + 3);
        STAGE(A, m0 + 128, smA1 + 8192, e + 3);
        STAGE(Bt, n0, smB1, e + 3);
        STAGE(Bt, n0 + 128, smB1 + 8192, e + 3);
        PRIO_MFQ(4, 0);
        VBAR(8);  // drain tile e+2 (4+4); e+3's 8 stay in flight
    }
    // ---- peeled last pair (K-tiles NT-2, NT-1): no stages ----
    LDA4(smA0, 0);
    LDB2(smB0, 0);
    LDB2(smB0, 2);
    PRIO_MFQ(0, 0);
    PRIO_MFQ(0, 2);
    LDA4(smA0, 4);
    PRIO_MFQ(4, 2);
    PRIO_MFQ(4, 0);
    VBAR(0);  // drain tile NT-1's 8 before reading buf1
    LDA4(smA1, 0);
    LDB2(smB1, 0);
    LDB2(smB1, 2);
    PRIO_MFQ(0, 0);
    PRIO_MFQ(0, 2);
    LDA4(smA1, 4);
    PRIO_MFQ(4, 2);
    PRIO_MFQ(4, 0);

    __syncthreads();  // drain everything before LDS reuse in epilogue

    // ---- epilogue: n-tile spans 2 heads of one of {q,k,v} ----
    const int which = n0 >> 11;           // 0=q 1=k 2=v
    const int h0 = (n0 & 2047) >> 7;      // first head in tile (even)
    const int bb = m0 >> 11, t0 = m0 & 2047;
    float bvv[4];
#pragma unroll
    for (int nn = 0; nn < 4; ++nn) bvv[nn] = bias[n0 + wc * 64 + nn * 16 + low];

    if (which < 2) {
        // q/k: [bh][t][d] with fused RoPE. epi tile [256][136] bf16 per head-half.
        u16* dstb = (which == 0 ? qb : kb);
        u16* epi = sm;
#pragma unroll
        for (int hh = 0; hh < 2; ++hh) {
            if ((wc >> 1) == hh) {
#pragma unroll
                for (int mm = 0; mm < 8; ++mm)
#pragma unroll
                    for (int nn = 0; nn < 4; ++nn)
#pragma unroll
                        for (int rr = 0; rr < 4; ++rr)
                            epi[(wr * 128 + mm * 16 + quad * 4 + rr) * 136 +
                                (wc & 1) * 64 + nn * 16 + low] = f2bf(acc[mm][nn][rr] + bvv[nn]);
            }
            __syncthreads();
            {
                const int row = tid >> 1, dh = (tid & 1) * 64;
                const int t = t0 + row;
                u16* dr = dstb + (((size_t)(bb * NHEAD + h0 + hh)) * TSEQ + t) * HDIM + dh;
                u16 vals[64];
#pragma unroll
                for (int qq = 0; qq < 8; ++qq)
                    *(short8*)(vals + qq * 8) = *(const short8*)(epi + row * 136 + dh + qq * 8);
                float csv[32], snv[32];
#pragma unroll
                for (int qq = 0; qq < 8; ++qq) {
                    *(float4*)(csv + qq * 4) =
                        *(const float4*)(cosp + (size_t)t * 64 + (dh >> 1) + qq * 4);
                    *(float4*)(snv + qq * 4) =
                        *(const float4*)(sinp + (size_t)t * 64 + (dh >> 1) + qq * 4);
                }
                u16 ov[64];
#pragma unroll
                for (int pp = 0; pp < 32; ++pp) {
                    float x0 = b2f(vals[2 * pp]), x1 = b2f(vals[2 * pp + 1]);
                    ov[2 * pp] = f2bf(x0 * csv[pp] - x1 * snv[pp]);
                    ov[2 * pp + 1] = f2bf(x0 * snv[pp] + x1 * csv[pp]);
                }
#pragma unroll
                for (int qq = 0; qq < 8; ++qq)
                    *(short8*)(dr + qq * 8) = *(const short8*)(ov + qq * 8);
            }
            __syncthreads();
        }
    } else {
        // v: write transposed [bh][d][t]. epi tile [128 d][264 (256 t + pad)] per head-half.
        u16* epi = sm;
#pragma unroll
        for (int hh = 0; hh < 2; ++hh) {
            if ((wc >> 1) == hh) {
#pragma unroll
                for (int mm = 0; mm < 8; ++mm)
#pragma unroll
                    for (int nn = 0; nn < 4; ++nn)
#pragma unroll
                        for (int rr = 0; rr < 4; ++rr)
                            epi[((wc & 1) * 64 + nn * 16 + low) * 264 +
                                wr * 128 + mm * 16 + quad * 4 + rr] = f2bf(acc[mm][nn][rr] + bvv[nn]);
            }
            __syncthreads();
            {
                const int dd = tid >> 2, tc = (tid & 3) * 64;
                u16* dr = vT + ((size_t)(bb * NHEAD + h0 + hh) * HDIM + dd) * TSEQ + t0 + tc;
#pragma unroll
                for (int qq = 0; qq < 8; ++qq)
                    *(short8*)(dr + qq * 8) = *(const short8*)(epi + dd * 264 + tc + qq * 8);
            }
            __syncthreads();
        }
    }
}

// ---------------- proj GEMM: out(f32) = y(bf16) @ WpT(bf16) + bias ----------------
// 128x256 tile, BK=64, 8 waves 2M x 4N (64x64/wave). Grid 32x8 = 256 blocks = 1/CU exact.
// Same T2 swizzle + barrier-light counted-vmcnt schedule. Direct f32 store epilogue.
#define PMFQ(NB)                                                                                      \
    {                                                                                                 \
        _Pragma("unroll") for (int mm = 0; mm < 4; ++mm) _Pragma("unroll") for (int nn = 0; nn < 2;   \
                                                                                ++nn) {               \
            acc[mm][(NB) + nn] = __builtin_amdgcn_mfma_f32_16x16x32_bf16(                             \
                a[mm][0], b[(NB) + nn][0], acc[mm][(NB) + nn], 0, 0, 0);                              \
            acc[mm][(NB) + nn] = __builtin_amdgcn_mfma_f32_16x16x32_bf16(                             \
                a[mm][1], b[(NB) + nn][1], acc[mm][(NB) + nn], 0, 0, 0);                              \
        }                                                                                             \
    }
#define PPRIO_MFQ(NB)                   \
    {                                   \
        __builtin_amdgcn_s_setprio(1);  \
        PMFQ(NB);                       \
        __builtin_amdgcn_s_setprio(0);  \
    }

__global__ __launch_bounds__(512, 2) void pgemm(
    const u16* __restrict__ A, const u16* __restrict__ Bt, const float* __restrict__ bias,
    float* __restrict__ outf, int M, int N, int K) {
    extern __shared__ u16 sm[];
    u16* const smA0 = sm;             // 128x64
    u16* const smB0 = sm + 8192;      // 256x64
    u16* const smA1 = sm + 24576;
    u16* const smB1 = sm + 32768;     // total 49152 u16 = 96 KiB

    const int tid = threadIdx.x;
    const int wave = tid >> 6, lane = tid & 63;
    const int low = lane & 15, quad = lane >> 4;
    const int wr = wave >> 2, wc = wave & 3;
    const int m0 = blockIdx.y * 128, n0 = blockIdx.x * 256;
    const int NT = K >> 6;

    const int grow = lane >> 3;
    const int gslot = (lane & 7) ^ grow;

    const int swz = low & 7;
    const int arow = (wr * 64 + low) * 64;
    const int brow = (wc * 64 + low) * 64;
    const int aoff0 = arow + ((0 + quad) ^ swz) * 8;
    const int aoff1 = arow + ((4 + quad) ^ swz) * 8;
    const int boff0 = brow + ((0 + quad) ^ swz) * 8;
    const int boff1 = brow + ((4 + quad) ^ swz) * 8;

    f32x4 acc[4][4];
#pragma unroll
    for (int i = 0; i < 4; i++)
#pragma unroll
        for (int j = 0; j < 4; j++) acc[i][j] = zero4();
    short8 a[4][2], b[4][2];

    // ---- prologue: tile0 -> buf0 (6 loads/thread), tile1 -> buf1 (6) ----
    STAGE(A, m0, smA0, 0);
    STAGE(Bt, n0, smB0, 0);
    STAGE(Bt, n0 + 128, smB0 + 8192, 0);
    STAGE(A, m0, smA1, 1);
    STAGE(Bt, n0, smB1, 1);
    STAGE(Bt, n0 + 128, smB1 + 8192, 1);
    VBAR(6);  // tile0 landed; tile1 (6) in flight

    const int NI = (NT >> 1) - 1;
#pragma unroll 1
    for (int it = 0; it < NI; ++it) {
        const int e = it * 2;
        // ---- K-tile e (buf0) ----
        LDA4(smA0, 0);
        LDB2(smB0, 0);
        LDB2(smB0, 2);
        PPRIO_MFQ(0);
        WAIT_DS();
        BAR();  // all buf0 reads retired -> restage buf0
        STAGE(A, m0, smA0, e + 2);
        STAGE(Bt, n0, smB0, e + 2);
        STAGE(Bt, n0 + 128, smB0 + 8192, e + 2);
        PPRIO_MFQ(2);
        VBAR(6);  // drain tile e+1 (6, staged last iter); e+2's 6 in flight
        // ---- K-tile e+1 (buf1) ----
        LDA4(smA1, 0);
        LDB2(smB1, 0);
        LDB2(smB1, 2);
        PPRIO_MFQ(0);
        WAIT_DS();
        BAR();
        STAGE(A, m0, smA1, e + 3);
        STAGE(Bt, n0, smB1, e + 3);
        STAGE(Bt, n0 + 128, smB1 + 8192, e + 3);
        PPRIO_MFQ(2);
        VBAR(6);  // drain tile e+2; e+3's 6 in flight
    }
    // ---- peeled last pair: no stages ----
    LDA4(smA0, 0);
    LDB2(smB0, 0);
    LDB2(smB0, 2);
    PPRIO_MFQ(0);
    PPRIO_MFQ(2);
    VBAR(0);  // drain tile NT-1 before reading buf1
    LDA4(smA1, 0);
    LDB2(smB1, 0);
    LDB2(smB1, 2);
    PPRIO_MFQ(0);
    PPRIO_MFQ(2);

    // ---- epilogue: direct coalesced f32 stores ----
    float bvv[4];
#pragma unroll
    for (int nn = 0; nn < 4; ++nn) bvv[nn] = bias[n0 + wc * 64 + nn * 16 + low];
#pragma unroll
    for (int mm = 0; mm < 4; ++mm) {
        const int rbase = m0 + wr * 64 + mm * 16 + quad * 4;
#pragma unroll
        for (int nn = 0; nn < 4; ++nn) {
            const int col = n0 + wc * 64 + nn * 16 + low;
#pragma unroll
            for (int r = 0; r < 4; ++r)
                outf[(size_t)(rbase + r) * N + col] = acc[mm][nn][r] + bvv[nn];
        }
    }
}

// ---------------- Flash attention: LDS-staged K/V, 64-key tiles, DPP softmax ----------------
__global__ __launch_bounds__(256) void flash_attn(const u16* __restrict__ qb, const u16* __restrict__ kb,
                                                  const u16* __restrict__ vT, u16* __restrict__ y) {
    __shared__ u16 Ks[64 * 128];      // [key][d], chunks xor-swizzled by (key&7)
    __shared__ u16 Vs[128 * 64];      // [d][key], chunks xor-swizzled by (d&7)
    __shared__ u16 Ps[4][16 * 72];    // per-wave P 16x64, row stride 72
    const int tid = threadIdx.x;
    const int wave = tid >> 6, lane = tid & 63;
    const int low = lane & 15, quad = lane >> 4;
    const int bh = blockIdx.x;
    const int qt = 31 - blockIdx.y;          // longest blocks first
    const int q0 = qt * 64 + wave * 16;
    const float scale2 = 0.08838834764831845f * 1.44269504088896f;  // 1/sqrt(128) * log2(e)

    const u16* Qp = qb + ((size_t)bh * TSEQ + q0) * HDIM;
    short8 qf[4];
#pragma unroll
    for (int c = 0; c < 4; c++) qf[c] = *(const short8*)(Qp + (size_t)low * HDIM + c * 32 + quad * 8);

    f32x4 o[8];
#pragma unroll
    for (int d = 0; d < 8; d++) o[d] = zero4();
    float m_i[4], l_i[4];
#pragma unroll
    for (int r = 0; r < 4; r++) { m_i[r] = -1e30f; l_i[r] = 0.f; }

    const u16* Kb = kb + (size_t)bh * TSEQ * HDIM;
    const u16* Vb = vT + (size_t)bh * HDIM * TSEQ;
    u16* Pw = &Ps[wave][0];
    const int ntiles = qt + 1;

    const int krow = tid >> 4, kchunk = tid & 15;   // K: 16 rows x 16 chunks per issue
    const int vrow = tid >> 3, vchunk = tid & 7;    // V: 32 rows x 8 chunks per issue

    for (int kt = 0; kt < ntiles; ++kt) {
        const int kv0 = kt * 64;
#pragma unroll
        for (int j = 0; j < 4; j++) {
            const int row = j * 16 + krow;
            const int gc = kchunk ^ (row & 7);
            async16(Kb + (size_t)(kv0 + row) * HDIM + gc * 8, Ks + row * 128 + kchunk * 8);
        }
#pragma unroll
        for (int j = 0; j < 4; j++) {
            const int d = j * 32 + vrow;
            const int gc = vchunk ^ (d & 7);
            async16(Vb + (size_t)d * TSEQ + kv0 + gc * 8, Vs + d * 64 + vchunk * 8);
        }
        __syncthreads();

        // ---- QK^T: S[16q x 64k] ----
        f32x4 s[4];
#pragma unroll
        for (int h = 0; h < 4; h++) s[h] = zero4();
#pragma unroll
        for (int h = 0; h < 4; h++) {
            const int row = h * 16 + low;
#pragma unroll
            for (int c = 0; c < 4; c++) {
                const int cc = c * 4 + quad;
                short8 kf = *(const short8*)(Ks + row * 128 + (cc ^ (row & 7)) * 8);
                s[h] = __builtin_amdgcn_mfma_f32_16x16x32_bf16(qf[c], kf, s[h], 0, 0, 0);
            }
        }

        // ---- online softmax (exp2 domain), DPP reductions ----
        float alpha[4];
#pragma unroll
        for (int r = 0; r < 4; r++) {
            const int qg = q0 + quad * 4 + r;
            float sv[4];
#pragma unroll
            for (int h = 0; h < 4; h++)
                sv[h] = (kv0 + h * 16 + low <= qg) ? s[h][r] * scale2 : -1e30f;
            float mx = fmaxf(fmaxf(sv[0], sv[1]), fmaxf(sv[2], sv[3]));
            mx = dpp_max16(mx);
            float mnew = fmaxf(m_i[r], mx);
            alpha[r] = exp2f(m_i[r] - mnew);
            m_i[r] = mnew;
            float p0 = exp2f(sv[0] - mnew);
            float p1 = exp2f(sv[1] - mnew);
            float p2 = exp2f(sv[2] - mnew);
            float p3 = exp2f(sv[3] - mnew);
            float rs = (p0 + p1) + (p2 + p3);
            rs = dpp_sum16(rs);
            l_i[r] = l_i[r] * alpha[r] + rs;
            const int prow = (quad * 4 + r) * 72;
            Pw[prow + low] = f2bf(p0);
            Pw[prow + 16 + low] = f2bf(p1);
            Pw[prow + 32 + low] = f2bf(p2);
            Pw[prow + 48 + low] = f2bf(p3);
        }
        __threadfence_block();

#pragma unroll
        for (int d = 0; d < 8; ++d)
#pragma unroll
            for (int r = 0; r < 4; r++) o[d][r] *= alpha[r];

        // ---- PV ----
#pragma unroll
        for (int kc = 0; kc < 2; kc++) {
            short8 pf = *(const short8*)(Pw + low * 72 + kc * 32 + quad * 8);
#pragma unroll
            for (int dd = 0; dd < 8; ++dd) {
                const int vr = dd * 16 + low;
                const int cc = kc * 4 + quad;
                short8 vf = *(const short8*)(Vs + vr * 64 + (cc ^ (vr & 7)) * 8);
                o[dd] = __builtin_amdgcn_mfma_f32_16x16x32_bf16(pf, vf, o[dd], 0, 0, 0);
            }
        }
        __syncthreads();
    }

    const int b = bh >> 4, h = bh & 15;
#pragma unroll
    for (int r = 0; r < 4; r++) {
        float inv = 1.0f / l_i[r];
        size_t row = (size_t)(b * TSEQ + q0 + quad * 4 + r);
        u16* yp = y + row * 2048 + h * HDIM;
#pragma unroll
        for (int d = 0; d < 8; ++d) yp[d * 16 + low] = f2bf(o[d][r] * inv);
    }
}

extern "C" void kernel_launch(void* const* d_in, const int* in_sizes, int n_in,
                              void* d_out, int out_size, void* d_ws, size_t ws_size,
                              hipStream_t stream) {
    const float* x = (const float*)d_in[0];
    const float* Wa = (const float*)d_in[1];
    const float* ba = (const float*)d_in[2];
    const float* Wp = (const float*)d_in[3];
    const float* bp = (const float*)d_in[4];
    const float* cs = (const float*)d_in[5];
    const float* sn = (const float*)d_in[6];
    float* out = (float*)d_out;

    u16* xb = (u16*)d_ws;             // x bf16; reused later as y
    u16* Wab = xb + 8388608;          // W_attn^T bf16 [6144][2048]
    u16* Wpb = Wab + 12582912;        // W_proj^T bf16 [2048][2048]
    u16* qb = Wpb + 4194304;          // [bh][t][d]
    u16* kb = qb + 8388608;           // [bh][t][d]
    u16* vT = kb + 8388608;           // [bh][d][t]
    u16* y = xb;

    static bool attr_set = false;
    if (!attr_set) {
        hipFuncSetAttribute(reinterpret_cast<const void*>(gemm256),
                            hipFuncAttributeMaxDynamicSharedMemorySize, 131072);
        hipFuncSetAttribute(reinterpret_cast<const void*>(pgemm),
                            hipFuncAttributeMaxDynamicSharedMemorySize, 98304);
        attr_set = true;
    }

    cast_bf16<<<8192, 256, 0, stream>>>((const float4*)x, (ushort4*)xb, 2097152);
    transpose_cast<<<dim3(96, 32), 256, 0, stream>>>(Wa, Wab, 2048, 6144);
    transpose_cast<<<dim3(32, 32), 256, 0, stream>>>(Wp, Wpb, 2048, 2048);
    gemm256<<<dim3(24, 16), 512, 131072, stream>>>(xb, Wab, ba, qb, kb, vT, cs, sn, 4096, 6144, 2048);
    flash_attn<<<dim3(32, 32), 256, 0, stream>>>(qb, kb, vT, y);
    pgemm<<<dim3(8, 32), 512, 98304, stream>>>(y, Wpb, bp, out, 4096, 2048, 2048);
}